// Round 1
// baseline (558.168 us; speedup 1.0000x reference)
//
#include <hip/hip_runtime.h>

// VectorQuantizer: inputs [65536,128] f32, codebook [1024,128] f32.
// Outputs flat f32: loss(1) | quantized_st(65536*128) | perplexity(1) | encodings(65536*1024)
#define NROWS 65536
#define DIM   128
#define KC    1024
#define QST_OFF  1
#define PPL_OFF  8388609
#define ENC_OFF  8388610

// --- rounding-exact helpers: replicate numpy's elementwise fp32 ops, no FMA contraction ---
__device__ __forceinline__ float fadd_rn_(float a, float b) {
#pragma clang fp contract(off)
  return a + b;
}
__device__ __forceinline__ float fsub_rn_(float a, float b) {
#pragma clang fp contract(off)
  return a - b;
}
__device__ __forceinline__ float fmul_rn_(float a, float b) {
#pragma clang fp contract(off)
  return a * b;
}

// K1: row sum-of-squares with numpy pairwise_sum order (n=128: 8 accumulators,
// 15 strided passes, combine ((r0+r1)+(r2+r3))+((r4+r5)+(r6+r7))).
__global__ __launch_bounds__(256) void k_rowsq(const float* __restrict__ inp,
                                               const float* __restrict__ cb,
                                               float* __restrict__ xx,
                                               float* __restrict__ cc) {
  int tid = blockIdx.x * 256 + threadIdx.x;
  const float* src;
  float* dst;
  if (tid < NROWS) {
    src = inp + (size_t)tid * DIM;
    dst = xx + tid;
  } else if (tid < NROWS + KC) {
    src = cb + (size_t)(tid - NROWS) * DIM;
    dst = cc + (tid - NROWS);
  } else {
    return;
  }
  float r[8];
  {
    float4 v0 = *(const float4*)(src);
    float4 v1 = *(const float4*)(src + 4);
    r[0] = fmul_rn_(v0.x, v0.x); r[1] = fmul_rn_(v0.y, v0.y);
    r[2] = fmul_rn_(v0.z, v0.z); r[3] = fmul_rn_(v0.w, v0.w);
    r[4] = fmul_rn_(v1.x, v1.x); r[5] = fmul_rn_(v1.y, v1.y);
    r[6] = fmul_rn_(v1.z, v1.z); r[7] = fmul_rn_(v1.w, v1.w);
  }
  for (int t = 1; t < 16; ++t) {
    float4 v0 = *(const float4*)(src + t * 8);
    float4 v1 = *(const float4*)(src + t * 8 + 4);
    r[0] = fadd_rn_(r[0], fmul_rn_(v0.x, v0.x));
    r[1] = fadd_rn_(r[1], fmul_rn_(v0.y, v0.y));
    r[2] = fadd_rn_(r[2], fmul_rn_(v0.z, v0.z));
    r[3] = fadd_rn_(r[3], fmul_rn_(v0.w, v0.w));
    r[4] = fadd_rn_(r[4], fmul_rn_(v1.x, v1.x));
    r[5] = fadd_rn_(r[5], fmul_rn_(v1.y, v1.y));
    r[6] = fadd_rn_(r[6], fmul_rn_(v1.z, v1.z));
    r[7] = fadd_rn_(r[7], fmul_rn_(v1.w, v1.w));
  }
  float res = fadd_rn_(fadd_rn_(fadd_rn_(r[0], r[1]), fadd_rn_(r[2], r[3])),
                       fadd_rn_(fadd_rn_(r[4], r[5]), fadd_rn_(r[6], r[7])));
  *dst = res;
}

// K2: per block: 64 rows. fp32 GEMM-style distance + argmin over all K=1024,
// then epilogue writes quantized_st rows, one-hot encodings rows (incl. zeros),
// count histogram atomics, loss partial sum.
__global__ __launch_bounds__(256) void k_main(const float* __restrict__ inp,
                                              const float* __restrict__ cb,
                                              const float* __restrict__ xx,
                                              const float* __restrict__ cc,
                                              float* __restrict__ out_qst,   // d_out + QST_OFF
                                              float* __restrict__ out_enc,   // d_out + ENC_OFF
                                              int* __restrict__ cnt,
                                              float* __restrict__ lsum) {
  // 64 KB exactly: As [128 d][64 row], Bs [128 d][64 code]; both overlaid later.
  __shared__ float As[DIM * 64];
  __shared__ float Bs[DIM * 64];
  int t = threadIdx.x;
  int tx = t & 15, ty = t >> 4;      // 16x16 thread tile; wave = 4 ty-groups
  int ty4 = ty * 4, tx4 = tx * 4;
  int row0 = blockIdx.x * 64;

  float xr[4];
#pragma unroll
  for (int i = 0; i < 4; ++i) xr[i] = xx[row0 + ty4 + i];

  // stage A transposed: thread t -> row t&63, d-segment (t>>6)*32
  {
    int r = t & 63, seg = t >> 6;
    const float* src = inp + (size_t)(row0 + r) * DIM + seg * 32;
#pragma unroll
    for (int i = 0; i < 8; ++i) {
      float4 v = *(const float4*)(src + i * 4);
      int d = seg * 32 + i * 4;
      As[d * 64 + r] = v.x;
      As[(d + 1) * 64 + r] = v.y;
      As[(d + 2) * 64 + r] = v.z;
      As[(d + 3) * 64 + r] = v.w;
    }
  }

  float bestv[4];
  int bestk[4];
#pragma unroll
  for (int i = 0; i < 4; ++i) { bestv[i] = 3.4e38f; bestk[i] = 0; }

  __syncthreads();

  for (int kt = 0; kt < 16; ++kt) {
    if (kt) __syncthreads();
    {
      int c = t & 63, seg = t >> 6;
      const float* src = cb + (size_t)(kt * 64 + c) * DIM + seg * 32;
#pragma unroll
      for (int i = 0; i < 8; ++i) {
        float4 v = *(const float4*)(src + i * 4);
        int d = seg * 32 + i * 4;
        Bs[d * 64 + c] = v.x;
        Bs[(d + 1) * 64 + c] = v.y;
        Bs[(d + 2) * 64 + c] = v.z;
        Bs[(d + 3) * 64 + c] = v.w;
      }
    }
    __syncthreads();

    float ccj[4];
#pragma unroll
    for (int j = 0; j < 4; ++j) ccj[j] = cc[kt * 64 + tx4 + j];

    float acc[4][4];
#pragma unroll
    for (int i = 0; i < 4; ++i)
#pragma unroll
      for (int j = 0; j < 4; ++j) acc[i][j] = 0.f;

#pragma unroll 8
    for (int d = 0; d < DIM; ++d) {
      float4 a = *(const float4*)&As[d * 64 + ty4];
      float4 b = *(const float4*)&Bs[d * 64 + tx4];
      acc[0][0] = __builtin_fmaf(a.x, b.x, acc[0][0]);
      acc[0][1] = __builtin_fmaf(a.x, b.y, acc[0][1]);
      acc[0][2] = __builtin_fmaf(a.x, b.z, acc[0][2]);
      acc[0][3] = __builtin_fmaf(a.x, b.w, acc[0][3]);
      acc[1][0] = __builtin_fmaf(a.y, b.x, acc[1][0]);
      acc[1][1] = __builtin_fmaf(a.y, b.y, acc[1][1]);
      acc[1][2] = __builtin_fmaf(a.y, b.z, acc[1][2]);
      acc[1][3] = __builtin_fmaf(a.y, b.w, acc[1][3]);
      acc[2][0] = __builtin_fmaf(a.z, b.x, acc[2][0]);
      acc[2][1] = __builtin_fmaf(a.z, b.y, acc[2][1]);
      acc[2][2] = __builtin_fmaf(a.z, b.z, acc[2][2]);
      acc[2][3] = __builtin_fmaf(a.z, b.w, acc[2][3]);
      acc[3][0] = __builtin_fmaf(a.w, b.x, acc[3][0]);
      acc[3][1] = __builtin_fmaf(a.w, b.y, acc[3][1]);
      acc[3][2] = __builtin_fmaf(a.w, b.z, acc[3][2]);
      acc[3][3] = __builtin_fmaf(a.w, b.w, acc[3][3]);
    }

    // distance = fl(fl(xx+cc) - fl(2*m)) -- numpy-exact rounding; first-index argmin
#pragma unroll
    for (int i = 0; i < 4; ++i) {
#pragma unroll
      for (int j = 0; j < 4; ++j) {
        float dist = fsub_rn_(fadd_rn_(xr[i], ccj[j]), fmul_rn_(2.0f, acc[i][j]));
        int idx = kt * 64 + tx4 + j;
        if (dist < bestv[i]) { bestv[i] = dist; bestk[i] = idx; }
      }
    }
  }

  // butterfly argmin across the 16 tx lanes (same wave); tie -> lower index
#pragma unroll
  for (int i = 0; i < 4; ++i) {
    float v = bestv[i];
    int k = bestk[i];
    for (int off = 1; off < 16; off <<= 1) {
      float ov = __shfl_xor(v, off);
      int ok = __shfl_xor(k, off);
      if (ov < v || (ov == v && ok < k)) { v = ov; k = ok; }
    }
    bestk[i] = k;
  }

  __syncthreads();  // all LDS reads done; safe to overlay
  int* bk = (int*)Bs;        // overlay bk[64] onto Bs
  float* red = As;           // overlay reduction scratch onto As
  if (tx == 0) {
#pragma unroll
    for (int i = 0; i < 4; ++i) {
      bk[ty4 + i] = bestk[i];
      atomicAdd(&cnt[bestk[i]], 1);
    }
  }
  __syncthreads();

  // quantized_st rows + loss partial (coalesced; x re-read from global, L2-hot)
  float ls = 0.f;
#pragma unroll 4
  for (int it = 0; it < 32; ++it) {
    int f = it * 256 + t;          // 0..8191 over 64 rows x 128 d
    int row = f >> 7, d = f & 127;
    size_t gro = (size_t)(row0 + row) * DIM + d;
    float x = inp[gro];
    float q = cb[(size_t)bk[row] * DIM + d];
    float qe = fsub_rn_(q, x);
    out_qst[gro] = fadd_rn_(x, qe);   // == np: inputs + (quantized - inputs)
    ls = __builtin_fmaf(qe, qe, ls);
  }

  // encodings rows: full zero+one-hot, float2 stores (base offset ≡ 2 mod 4 floats)
  for (int it = 0; it < 128; ++it) {
    int f2 = it * 256 + t;         // 0..32767 over 64 rows x 512 float2
    int row = f2 >> 9, c2 = f2 & 511;
    int kk = bk[row];
    float2 v;
    v.x = (kk == 2 * c2) ? 1.0f : 0.0f;
    v.y = (kk == 2 * c2 + 1) ? 1.0f : 0.0f;
    *(float2*)&out_enc[(size_t)(row0 + row) * KC + 2 * c2] = v;
  }

  // block loss reduce -> one atomic
  for (int off = 32; off; off >>= 1) ls += __shfl_down(ls, off);
  if ((t & 63) == 0) red[t >> 6] = ls;
  __syncthreads();
  if (t == 0) {
    float s = red[0] + red[1] + red[2] + red[3];
    atomicAdd(lsum, s);
  }
}

// K3: loss + perplexity scalars
__global__ __launch_bounds__(1024) void k_scalars(const int* __restrict__ cnt,
                                                  const float* __restrict__ lsum,
                                                  float* __restrict__ out) {
  int t = threadIdx.x;
  float p = (float)cnt[t] * (1.0f / 65536.0f);
  float term = fmul_rn_(p, __logf(fadd_rn_(p, 1e-10f)) * 0.69314718055994530942f);
  // NOTE: __logf is log2-based fast; use precise logf instead:
  term = fmul_rn_(p, logf(fadd_rn_(p, 1e-10f)));
  for (int off = 32; off; off >>= 1) term += __shfl_down(term, off);
  __shared__ float red[16];
  if ((t & 63) == 0) red[t >> 6] = term;
  __syncthreads();
  if (t == 0) {
    float s = 0.f;
#pragma unroll
    for (int w = 0; w < 16; ++w) s += red[w];
    out[PPL_OFF] = expf(-s);
    float e = *lsum * (1.0f / 8388608.0f);
    out[0] = fadd_rn_(e, fmul_rn_(0.25f, e));  // q_latent + 0.25*e_latent (equal values)
  }
}

extern "C" void kernel_launch(void* const* d_in, const int* in_sizes, int n_in,
                              void* d_out, int out_size, void* d_ws, size_t ws_size,
                              hipStream_t stream) {
  const float* inp = (const float*)d_in[0];
  const float* cb = (const float*)d_in[1];
  float* out = (float*)d_out;
  float* xx = (float*)d_ws;              // 65536 f32
  float* cc = xx + NROWS;                // 1024 f32
  int* cnt = (int*)(cc + KC);            // 1024 i32
  float* lsum = (float*)(cnt + KC);      // 1 f32

  hipMemsetAsync(cnt, 0, (KC + 1) * sizeof(int), stream);
  k_rowsq<<<(NROWS + KC) / 256, 256, 0, stream>>>(inp, cb, xx, cc);
  k_main<<<NROWS / 64, 256, 0, stream>>>(inp, cb, xx, cc,
                                         out + QST_OFF, out + ENC_OFF, cnt, lsum);
  k_scalars<<<1, 1024, 0, stream>>>(cnt, lsum, out);
}